// Round 2
// baseline (5445.522 us; speedup 1.0000x reference)
//
#include <hip/hip_runtime.h>

#define NROWS 1568      // BATCH * L = 8 * 196
#define LSEQ  196
#define EPS   1e-5f

__device__ __forceinline__ float silu_(float x) { return x / (1.f + expf(-x)); }

// ---------------- im2col for patch embedding ----------------
// A[m, r] = x[b, c, ph*16+i, pw*16+j],  m=(b,l), r=(c,i,j)  (1568 x 768)
__global__ __launch_bounds__(256) void im2col_k(const float* __restrict__ x,
                                                float* __restrict__ A) {
  int idx = blockIdx.x * 256 + threadIdx.x;
  if (idx >= NROWS * 768) return;
  int m = idx / 768, r = idx - m * 768;
  int b = m / LSEQ, l = m - b * LSEQ;
  int ph = l / 14, pw = l - ph * 14;
  int c = r >> 8, rem = r & 255, i = rem >> 4, j = rem & 15;
  A[idx] = x[((b * 3 + c) * 224 + ph * 16 + i) * 224 + pw * 16 + j];
}

// ---------------- generic tiled fp32 GEMM: C[M,N] = A[M,K] * W[N,K]^T (+bias) ----------------
#define BM 32
#define BN 64
#define BK 32
__global__ __launch_bounds__(256) void gemm_k(const float* __restrict__ A,
                                              const float* __restrict__ W,
                                              const float* __restrict__ bias,
                                              float* __restrict__ C,
                                              int N, int K) {
  __shared__ float As[BM][BK + 1];
  __shared__ float Ws[BN][BK + 1];
  int row0 = blockIdx.x * BM;
  int col0 = blockIdx.y * BN;
  int tid = threadIdx.x;
  int tc = tid & 15, tr = tid >> 4;
  float acc[2][4] = {{0.f, 0.f, 0.f, 0.f}, {0.f, 0.f, 0.f, 0.f}};
  for (int kk = 0; kk < K; kk += BK) {
#pragma unroll
    for (int i = 0; i < 4; ++i) {
      int idx = tid + i * 256;
      int m = idx >> 5, k = idx & 31;
      As[m][k] = A[(row0 + m) * K + kk + k];
    }
#pragma unroll
    for (int i = 0; i < 8; ++i) {
      int idx = tid + i * 256;
      int n = idx >> 5, k = idx & 31;
      Ws[n][k] = W[(col0 + n) * K + kk + k];
    }
    __syncthreads();
#pragma unroll
    for (int k = 0; k < BK; ++k) {
      float a0 = As[tr * 2 + 0][k], a1 = As[tr * 2 + 1][k];
      float w0 = Ws[tc * 4 + 0][k], w1 = Ws[tc * 4 + 1][k];
      float w2 = Ws[tc * 4 + 2][k], w3 = Ws[tc * 4 + 3][k];
      acc[0][0] += a0 * w0; acc[0][1] += a0 * w1; acc[0][2] += a0 * w2; acc[0][3] += a0 * w3;
      acc[1][0] += a1 * w0; acc[1][1] += a1 * w1; acc[1][2] += a1 * w2; acc[1][3] += a1 * w3;
    }
    __syncthreads();
  }
#pragma unroll
  for (int i = 0; i < 2; ++i) {
    int rr = row0 + tr * 2 + i;
#pragma unroll
    for (int j = 0; j < 4; ++j) {
      int cc = col0 + tc * 4 + j;
      float o = acc[i][j];
      if (bias) o += bias[cc];
      C[rr * N + cc] = o;
    }
  }
}

// ---------------- fused residual-add + LayerNorm (1 wave per row of 192) ----------------
__global__ __launch_bounds__(64) void addln_k(float* __restrict__ res,
                                              const float* __restrict__ h,
                                              const float* __restrict__ w,
                                              const float* __restrict__ b,
                                              float* __restrict__ out) {
  int n = blockIdx.x;
  int t = threadIdx.x;
  float v[3];
  float s = 0.f;
#pragma unroll
  for (int i = 0; i < 3; ++i) {
    int d = t + 64 * i;
    float r = res[n * 192 + d] + h[n * 192 + d];
    res[n * 192 + d] = r;
    v[i] = r;
    s += r;
  }
#pragma unroll
  for (int off = 32; off >= 1; off >>= 1) s += __shfl_xor(s, off);
  float mu = s * (1.f / 192.f);
  float q = 0.f;
#pragma unroll
  for (int i = 0; i < 3; ++i) { float dd = v[i] - mu; q += dd * dd; }
#pragma unroll
  for (int off = 32; off >= 1; off >>= 1) q += __shfl_xor(q, off);
  float inv = rsqrtf(q * (1.f / 192.f) + EPS);
#pragma unroll
  for (int i = 0; i < 3; ++i) {
    int d = t + 64 * i;
    out[n * 192 + d] = (v[i] - mu) * inv * w[d] + b[d];
  }
}

// ---------------- fused conv4+SiLU + x_proj + dt_proj (one block per row) ----------------
// xz: (NROWS, 768) -> xc (NROWS,384), dbl (NROWS,44), dt (NROWS,384)
__global__ __launch_bounds__(384) void convdbldt_k(const float* __restrict__ xz,
                                                   const float* __restrict__ cw,
                                                   const float* __restrict__ cb,
                                                   const float* __restrict__ xpw,
                                                   const float* __restrict__ dtw,
                                                   const float* __restrict__ dtb,
                                                   float* __restrict__ xc,
                                                   float* __restrict__ dbl,
                                                   float* __restrict__ dt) {
  __shared__ float xcl[384];
  __shared__ float dbll[44];
  int n = blockIdx.x;
  int b = n / LSEQ, l = n - b * LSEQ;
  int t = threadIdx.x;

  // phase 1: causal depthwise conv (K=4, left pad 3) + SiLU
  float acc = cb[t];
#pragma unroll
  for (int k = 0; k < 4; ++k) {
    int ll = l - 3 + k;
    if (ll >= 0) acc += xz[(size_t)(b * LSEQ + ll) * 768 + t] * cw[t * 4 + k];
  }
  float xcv = silu_(acc);
  xcl[t] = xcv;
  xc[(size_t)n * 384 + t] = xcv;
  __syncthreads();

  // phase 2: dbl[e] = dot(xc_row, xpw[e,:]), e in [0,44); 8 partial lanes per e
  if (t < 352) {
    int e = t >> 3, part = t & 7;
    float s2 = 0.f;
    const float* wrow = xpw + e * 384 + part * 48;
    const float* xrow = xcl + part * 48;
#pragma unroll 8
    for (int k = 0; k < 48; ++k) s2 += xrow[k] * wrow[k];
    s2 += __shfl_xor(s2, 1);
    s2 += __shfl_xor(s2, 2);
    s2 += __shfl_xor(s2, 4);
    if (part == 0) {
      dbll[e] = s2;
      dbl[(size_t)n * 44 + e] = s2;
    }
  }
  __syncthreads();

  // phase 3: dt[d] = softplus(dot(dbl[0:12], dtw[d,:]) + dtb[d])
  float a = dtb[t];
#pragma unroll
  for (int r = 0; r < 12; ++r) a += dbll[r] * dtw[t * 12 + r];
  float sp = fmaxf(a, 0.f) + log1pf(expf(-fabsf(a)));
  dt[(size_t)n * 384 + t] = sp;
}

// ---------------- selective scan: 16 lanes per (b,d), states in registers ----------------
__global__ __launch_bounds__(256) void scan_k(const float* __restrict__ dt,
                                              const float* __restrict__ xc,
                                              const float* __restrict__ dbl,
                                              const float* __restrict__ xz,
                                              const float* __restrict__ a_log,
                                              const float* __restrict__ dpar,
                                              float* __restrict__ y) {
  int t = threadIdx.x;
  int s = t & 15;
  int g = (blockIdx.x * 256 + t) >> 4;  // (b,d) pair, 0..3071
  int b = g / 384, d = g - b * 384;
  float A = -expf(a_log[d * 16 + s]);
  float Dp = dpar[d];
  float hst = 0.f;
  int base = b * LSEQ;
  for (int l = 0; l < LSEQ; ++l) {
    int n = base + l;
    float dtv = dt[(size_t)n * 384 + d];
    float xcv = xc[(size_t)n * 384 + d];
    float Bv = dbl[(size_t)n * 44 + 12 + s];
    float Cv = dbl[(size_t)n * 44 + 28 + s];
    float dA = expf(dtv * A);
    hst = dA * hst + dtv * xcv * Bv;
    float ps = hst * Cv;
    ps += __shfl_xor(ps, 1);
    ps += __shfl_xor(ps, 2);
    ps += __shfl_xor(ps, 4);
    ps += __shfl_xor(ps, 8);
    if (s == 0) {
      float zv = xz[(size_t)n * 768 + 384 + d];
      y[(size_t)n * 384 + d] = (ps + Dp * xcv) * silu_(zv);
    }
  }
}

extern "C" void kernel_launch(void* const* d_in, const int* in_sizes, int n_in,
                              void* d_out, int out_size, void* d_ws, size_t ws_size,
                              hipStream_t stream) {
  const float* x        = (const float*)d_in[0];
  const float* patch_w  = (const float*)d_in[1];
  const float* patch_b  = (const float*)d_in[2];
  const float* norm_w   = (const float*)d_in[3];
  const float* norm_b   = (const float*)d_in[4];
  const float* in_proj_w  = (const float*)d_in[5];
  const float* conv_w   = (const float*)d_in[6];
  const float* conv_b   = (const float*)d_in[7];
  const float* x_proj_w = (const float*)d_in[8];
  const float* dt_proj_w = (const float*)d_in[9];
  const float* dt_proj_b = (const float*)d_in[10];
  const float* A_log    = (const float*)d_in[11];
  const float* D_param  = (const float*)d_in[12];
  const float* out_proj_w = (const float*)d_in[13];
  const float* normf_w  = (const float*)d_in[14];
  const float* normf_b  = (const float*)d_in[15];
  float* out = (float*)d_out;
  float* ws = (float*)d_ws;

  // workspace layout (floats)
  float* res = ws;                  // 301056
  float* h   = ws + 301056;         // 301056
  float* hn  = ws + 602112;         // 301056
  float* xz  = ws + 903168;         // 1204224 (also reused as im2col buffer)
  float* xc  = ws + 2107392;        // 602112
  float* dbl = ws + 2709504;        // 68992
  float* dt  = ws + 2778496;        // 602112
  float* y   = ws + 3380608;        // 602112

  hipMemsetAsync(res, 0, 301056 * sizeof(float), stream);

  // patch embedding: im2col + GEMM (M=1568, N=192, K=768) + bias
  im2col_k<<<dim3((NROWS * 768 + 255) / 256), 256, 0, stream>>>(x, xz);
  {
    dim3 g(NROWS / BM, 192 / BN);
    gemm_k<<<g, 256, 0, stream>>>(xz, patch_w, patch_b, h, 192, 768);
  }

  for (int L = 0; L < 24; ++L) {
    addln_k<<<NROWS, 64, 0, stream>>>(res, h, norm_w + L * 192, norm_b + L * 192, hn);
    {
      dim3 g(NROWS / BM, 768 / BN);
      gemm_k<<<g, 256, 0, stream>>>(hn, in_proj_w + (size_t)L * 768 * 192, nullptr, xz, 768, 192);
    }
    convdbldt_k<<<NROWS, 384, 0, stream>>>(xz,
        conv_w + (size_t)L * 384 * 4, conv_b + (size_t)L * 384,
        x_proj_w + (size_t)L * 44 * 384,
        dt_proj_w + (size_t)L * 384 * 12, dt_proj_b + (size_t)L * 384,
        xc, dbl, dt);
    // 3072 (b,d) pairs * 16 lanes = 49152 threads -> 192 blocks of 256
    scan_k<<<dim3((8 * 384 * 16) / 256), 256, 0, stream>>>(dt, xc, dbl, xz,
        A_log + (size_t)L * 384 * 16, D_param + (size_t)L * 384, y);
    {
      dim3 g(NROWS / BM, 192 / BN);
      gemm_k<<<g, 256, 0, stream>>>(y, out_proj_w + (size_t)L * 192 * 384, nullptr, h, 192, 384);
    }
  }

  addln_k<<<NROWS, 64, 0, stream>>>(res, h, normf_w, normf_b, out);
}

// Round 3
// 2599.036 us; speedup vs baseline: 2.0952x; 2.0952x over previous
//
#include <hip/hip_runtime.h>

#define NROWS 1568      // BATCH * L = 8 * 196
#define LSEQ  196
#define EPS   1e-5f
#define TCH   14        // chunk length
#define NCH   14        // number of chunks (TCH*NCH == LSEQ)

__device__ __forceinline__ float silu_(float x) { return x / (1.f + expf(-x)); }

// ---------------- im2col for patch embedding ----------------
__global__ __launch_bounds__(256) void im2col_k(const float* __restrict__ x,
                                                float* __restrict__ A) {
  int idx = blockIdx.x * 256 + threadIdx.x;
  if (idx >= NROWS * 768) return;
  int m = idx / 768, r = idx - m * 768;
  int b = m / LSEQ, l = m - b * LSEQ;
  int ph = l / 14, pw = l - ph * 14;
  int c = r >> 8, rem = r & 255, i = rem >> 4, j = rem & 15;
  A[idx] = x[((b * 3 + c) * 224 + ph * 16 + i) * 224 + pw * 16 + j];
}

// ---------------- generic tiled fp32 GEMM: C[M,N] = A[M,K] * W[N,K]^T (+bias) ----------------
#define BM 32
#define BN 64
#define BK 32
__global__ __launch_bounds__(256) void gemm_k(const float* __restrict__ A,
                                              const float* __restrict__ W,
                                              const float* __restrict__ bias,
                                              float* __restrict__ C,
                                              int N, int K) {
  __shared__ float As[BM][BK + 1];
  __shared__ float Ws[BN][BK + 1];
  int row0 = blockIdx.x * BM;
  int col0 = blockIdx.y * BN;
  int tid = threadIdx.x;
  int tc = tid & 15, tr = tid >> 4;
  float acc[2][4] = {{0.f, 0.f, 0.f, 0.f}, {0.f, 0.f, 0.f, 0.f}};
  for (int kk = 0; kk < K; kk += BK) {
#pragma unroll
    for (int i = 0; i < 4; ++i) {
      int idx = tid + i * 256;
      int m = idx >> 5, k = idx & 31;
      As[m][k] = A[(row0 + m) * K + kk + k];
    }
#pragma unroll
    for (int i = 0; i < 8; ++i) {
      int idx = tid + i * 256;
      int n = idx >> 5, k = idx & 31;
      Ws[n][k] = W[(col0 + n) * K + kk + k];
    }
    __syncthreads();
#pragma unroll
    for (int k = 0; k < BK; ++k) {
      float a0 = As[tr * 2 + 0][k], a1 = As[tr * 2 + 1][k];
      float w0 = Ws[tc * 4 + 0][k], w1 = Ws[tc * 4 + 1][k];
      float w2 = Ws[tc * 4 + 2][k], w3 = Ws[tc * 4 + 3][k];
      acc[0][0] += a0 * w0; acc[0][1] += a0 * w1; acc[0][2] += a0 * w2; acc[0][3] += a0 * w3;
      acc[1][0] += a1 * w0; acc[1][1] += a1 * w1; acc[1][2] += a1 * w2; acc[1][3] += a1 * w3;
    }
    __syncthreads();
  }
#pragma unroll
  for (int i = 0; i < 2; ++i) {
    int rr = row0 + tr * 2 + i;
#pragma unroll
    for (int j = 0; j < 4; ++j) {
      int cc = col0 + tc * 4 + j;
      float o = acc[i][j];
      if (bias) o += bias[cc];
      C[rr * N + cc] = o;
    }
  }
}

// ---------------- fused residual-add + LayerNorm (1 wave per row of 192) ----------------
__global__ __launch_bounds__(64) void addln_k(float* __restrict__ res,
                                              const float* __restrict__ h,
                                              const float* __restrict__ w,
                                              const float* __restrict__ b,
                                              float* __restrict__ out) {
  int n = blockIdx.x;
  int t = threadIdx.x;
  float v[3];
  float s = 0.f;
#pragma unroll
  for (int i = 0; i < 3; ++i) {
    int d = t + 64 * i;
    float r = res[n * 192 + d] + h[n * 192 + d];
    res[n * 192 + d] = r;
    v[i] = r;
    s += r;
  }
#pragma unroll
  for (int off = 32; off >= 1; off >>= 1) s += __shfl_xor(s, off);
  float mu = s * (1.f / 192.f);
  float q = 0.f;
#pragma unroll
  for (int i = 0; i < 3; ++i) { float dd = v[i] - mu; q += dd * dd; }
#pragma unroll
  for (int off = 32; off >= 1; off >>= 1) q += __shfl_xor(q, off);
  float inv = rsqrtf(q * (1.f / 192.f) + EPS);
#pragma unroll
  for (int i = 0; i < 3; ++i) {
    int d = t + 64 * i;
    out[n * 192 + d] = (v[i] - mu) * inv * w[d] + b[d];
  }
}

// ---------------- fused conv4+SiLU + x_proj + dt_proj (one block per row) ----------------
__global__ __launch_bounds__(384) void convdbldt_k(const float* __restrict__ xz,
                                                   const float* __restrict__ cw,
                                                   const float* __restrict__ cb,
                                                   const float* __restrict__ xpw,
                                                   const float* __restrict__ dtw,
                                                   const float* __restrict__ dtb,
                                                   float* __restrict__ xc,
                                                   float* __restrict__ dbl,
                                                   float* __restrict__ dt) {
  __shared__ float xcl[384];
  __shared__ float dbll[44];
  int n = blockIdx.x;
  int b = n / LSEQ, l = n - b * LSEQ;
  int t = threadIdx.x;

  float acc = cb[t];
#pragma unroll
  for (int k = 0; k < 4; ++k) {
    int ll = l - 3 + k;
    if (ll >= 0) acc += xz[(size_t)(b * LSEQ + ll) * 768 + t] * cw[t * 4 + k];
  }
  float xcv = silu_(acc);
  xcl[t] = xcv;
  xc[(size_t)n * 384 + t] = xcv;
  __syncthreads();

  if (t < 352) {
    int e = t >> 3, part = t & 7;
    float s2 = 0.f;
    const float* wrow = xpw + e * 384 + part * 48;
    const float* xrow = xcl + part * 48;
#pragma unroll 8
    for (int k = 0; k < 48; ++k) s2 += xrow[k] * wrow[k];
    s2 += __shfl_xor(s2, 1);
    s2 += __shfl_xor(s2, 2);
    s2 += __shfl_xor(s2, 4);
    if (part == 0) {
      dbll[e] = s2;
      dbl[(size_t)n * 44 + e] = s2;
    }
  }
  __syncthreads();

  float a = dtb[t];
#pragma unroll
  for (int r = 0; r < 12; ++r) a += dbll[r] * dtw[t * 12 + r];
  float sp = fmaxf(a, 0.f) + log1pf(expf(-fabsf(a)));
  dt[(size_t)n * 384 + t] = sp;
}

// ---------------- chunked selective scan ----------------
// thread tid -> (c, b, d, s): s=tid&15, g=tid>>4, c=g/3072, bd=g%3072
// Pass A: local scan from h=0 over chunk c; emit P = prod(a), S = local final state.
__global__ __launch_bounds__(256) void scanA_k(const float* __restrict__ dt,
                                               const float* __restrict__ xc,
                                               const float* __restrict__ dbl,
                                               const float* __restrict__ a_log,
                                               float* __restrict__ P,
                                               float* __restrict__ S) {
  int tid = blockIdx.x * 256 + threadIdx.x;
  int s = tid & 15;
  int g = tid >> 4;
  int c = g / 3072;
  int bd = g - c * 3072;
  int b = bd / 384, d = bd - b * 384;
  float A = -expf(a_log[d * 16 + s]);
  float h = 0.f, p = 1.f;
  int l0 = c * TCH, base = b * LSEQ;
  for (int i = 0; i < TCH; ++i) {
    int n = base + l0 + i;
    float dtv = dt[(size_t)n * 384 + d];
    float xcv = xc[(size_t)n * 384 + d];
    float Bv = dbl[(size_t)n * 44 + 12 + s];
    float a = expf(dtv * A);
    h = a * h + dtv * xcv * Bv;
    p *= a;
  }
  P[tid] = p;
  S[tid] = h;
}

// Pass C: rebuild h_init from upstream (P,S), rescan chunk, write gated output.
__global__ __launch_bounds__(256) void scanC_k(const float* __restrict__ dt,
                                               const float* __restrict__ xc,
                                               const float* __restrict__ dbl,
                                               const float* __restrict__ xz,
                                               const float* __restrict__ a_log,
                                               const float* __restrict__ dpar,
                                               const float* __restrict__ P,
                                               const float* __restrict__ S,
                                               float* __restrict__ y) {
  int tid = blockIdx.x * 256 + threadIdx.x;
  int s = tid & 15;
  int g = tid >> 4;
  int c = g / 3072;           // uniform within a block (3072 % 16 == 0)
  int bd = g - c * 3072;
  int b = bd / 384, d = bd - b * 384;
  float A = -expf(a_log[d * 16 + s]);
  float Dp = dpar[d];
  float h = 0.f;
  for (int cc = 0; cc < c; ++cc) {
    int idx = ((cc * 3072 + bd) << 4) + s;
    h = P[idx] * h + S[idx];
  }
  int l0 = c * TCH, base = b * LSEQ;
  for (int i = 0; i < TCH; ++i) {
    int n = base + l0 + i;
    float dtv = dt[(size_t)n * 384 + d];
    float xcv = xc[(size_t)n * 384 + d];
    float Bv = dbl[(size_t)n * 44 + 12 + s];
    float Cv = dbl[(size_t)n * 44 + 28 + s];
    float a = expf(dtv * A);
    h = a * h + dtv * xcv * Bv;
    float ps = h * Cv;
    ps += __shfl_xor(ps, 1);
    ps += __shfl_xor(ps, 2);
    ps += __shfl_xor(ps, 4);
    ps += __shfl_xor(ps, 8);
    if (s == 0) {
      float zv = xz[(size_t)n * 768 + 384 + d];
      y[(size_t)n * 384 + d] = (ps + Dp * xcv) * silu_(zv);
    }
  }
}

// ---------------- fallback single-kernel scan (used if ws too small) ----------------
__global__ __launch_bounds__(256) void scan_k(const float* __restrict__ dt,
                                              const float* __restrict__ xc,
                                              const float* __restrict__ dbl,
                                              const float* __restrict__ xz,
                                              const float* __restrict__ a_log,
                                              const float* __restrict__ dpar,
                                              float* __restrict__ y) {
  int t = threadIdx.x;
  int s = t & 15;
  int g = (blockIdx.x * 256 + t) >> 4;
  int b = g / 384, d = g - b * 384;
  float A = -expf(a_log[d * 16 + s]);
  float Dp = dpar[d];
  float hst = 0.f;
  int base = b * LSEQ;
  for (int l = 0; l < LSEQ; ++l) {
    int n = base + l;
    float dtv = dt[(size_t)n * 384 + d];
    float xcv = xc[(size_t)n * 384 + d];
    float Bv = dbl[(size_t)n * 44 + 12 + s];
    float Cv = dbl[(size_t)n * 44 + 28 + s];
    float dA = expf(dtv * A);
    hst = dA * hst + dtv * xcv * Bv;
    float ps = hst * Cv;
    ps += __shfl_xor(ps, 1);
    ps += __shfl_xor(ps, 2);
    ps += __shfl_xor(ps, 4);
    ps += __shfl_xor(ps, 8);
    if (s == 0) {
      float zv = xz[(size_t)n * 768 + 384 + d];
      y[(size_t)n * 384 + d] = (ps + Dp * xcv) * silu_(zv);
    }
  }
}

extern "C" void kernel_launch(void* const* d_in, const int* in_sizes, int n_in,
                              void* d_out, int out_size, void* d_ws, size_t ws_size,
                              hipStream_t stream) {
  const float* x        = (const float*)d_in[0];
  const float* patch_w  = (const float*)d_in[1];
  const float* patch_b  = (const float*)d_in[2];
  const float* norm_w   = (const float*)d_in[3];
  const float* norm_b   = (const float*)d_in[4];
  const float* in_proj_w  = (const float*)d_in[5];
  const float* conv_w   = (const float*)d_in[6];
  const float* conv_b   = (const float*)d_in[7];
  const float* x_proj_w = (const float*)d_in[8];
  const float* dt_proj_w = (const float*)d_in[9];
  const float* dt_proj_b = (const float*)d_in[10];
  const float* A_log    = (const float*)d_in[11];
  const float* D_param  = (const float*)d_in[12];
  const float* out_proj_w = (const float*)d_in[13];
  const float* normf_w  = (const float*)d_in[14];
  const float* normf_b  = (const float*)d_in[15];
  float* out = (float*)d_out;
  float* ws = (float*)d_ws;

  // workspace layout (floats)
  float* res = ws;                  // 301056
  float* h   = ws + 301056;         // 301056
  float* hn  = ws + 602112;         // 301056
  float* xz  = ws + 903168;         // 1204224 (also im2col buffer)
  float* xc  = ws + 2107392;        // 602112
  float* dbl = ws + 2709504;        // 68992
  float* dt  = ws + 2778496;        // 602112
  float* y   = ws + 3380608;        // 602112
  float* Pb  = ws + 3982720;        // 688128 (NCH * 3072 * 16)
  float* Sb  = ws + 4670848;        // 688128
  const size_t need = (size_t)(4670848 + 688128) * sizeof(float);
  const bool chunked = ws_size >= need;

  hipMemsetAsync(res, 0, 301056 * sizeof(float), stream);

  im2col_k<<<dim3((NROWS * 768 + 255) / 256), 256, 0, stream>>>(x, xz);
  {
    dim3 g(NROWS / BM, 192 / BN);
    gemm_k<<<g, 256, 0, stream>>>(xz, patch_w, patch_b, h, 192, 768);
  }

  for (int L = 0; L < 24; ++L) {
    addln_k<<<NROWS, 64, 0, stream>>>(res, h, norm_w + L * 192, norm_b + L * 192, hn);
    {
      dim3 g(NROWS / BM, 768 / BN);
      gemm_k<<<g, 256, 0, stream>>>(hn, in_proj_w + (size_t)L * 768 * 192, nullptr, xz, 768, 192);
    }
    convdbldt_k<<<NROWS, 384, 0, stream>>>(xz,
        conv_w + (size_t)L * 384 * 4, conv_b + (size_t)L * 384,
        x_proj_w + (size_t)L * 44 * 384,
        dt_proj_w + (size_t)L * 384 * 12, dt_proj_b + (size_t)L * 384,
        xc, dbl, dt);
    const float* al = A_log + (size_t)L * 384 * 16;
    const float* dp = D_param + (size_t)L * 384;
    if (chunked) {
      scanA_k<<<dim3(NCH * 3072 * 16 / 256), 256, 0, stream>>>(dt, xc, dbl, al, Pb, Sb);
      scanC_k<<<dim3(NCH * 3072 * 16 / 256), 256, 0, stream>>>(dt, xc, dbl, xz, al, dp, Pb, Sb, y);
    } else {
      scan_k<<<dim3((8 * 384 * 16) / 256), 256, 0, stream>>>(dt, xc, dbl, xz, al, dp, y);
    }
    {
      dim3 g(NROWS / BM, 192 / BN);
      gemm_k<<<g, 256, 0, stream>>>(y, out_proj_w + (size_t)L * 192 * 384, nullptr, h, 192, 384);
    }
  }

  addln_k<<<NROWS, 64, 0, stream>>>(res, h, normf_w, normf_b, out);
}

// Round 4
// 1991.130 us; speedup vs baseline: 2.7349x; 1.3053x over previous
//
#include <hip/hip_runtime.h>

#define NROWS 1568      // BATCH * L = 8 * 196
#define MPAD  1600      // padded rows for 64-row GEMM tiles
#define LSEQ  196
#define EPS   1e-5f

typedef __attribute__((ext_vector_type(8))) short short8_t;   // 8 bf16
typedef __attribute__((ext_vector_type(8))) unsigned short ush8;
typedef __attribute__((ext_vector_type(4))) float f32x4;

__device__ __forceinline__ float silu_(float x) { return x / (1.f + expf(-x)); }

__device__ __forceinline__ unsigned short bfh_(float f) {
  unsigned u = __float_as_uint(f);
  unsigned r = (u + 0x7FFFu + ((u >> 16) & 1u)) >> 16;
  return (unsigned short)r;
}
__device__ __forceinline__ float bf2f_(unsigned short h) {
  unsigned u = ((unsigned)h) << 16;
  return __uint_as_float(u);
}

// ---------------- im2col for patch embedding ----------------
__global__ __launch_bounds__(256) void im2col_k(const float* __restrict__ x,
                                                float* __restrict__ A) {
  int idx = blockIdx.x * 256 + threadIdx.x;
  if (idx >= NROWS * 768) return;
  int m = idx / 768, r = idx - m * 768;
  int b = m / LSEQ, l = m - b * LSEQ;
  int ph = l / 14, pw = l - ph * 14;
  int c = r >> 8, rem = r & 255, i = rem >> 4, j = rem & 15;
  A[idx] = x[((b * 3 + c) * 224 + ph * 16 + i) * 224 + pw * 16 + j];
}

// ---------------- MFMA GEMM: C[MPAD,N] = A[MPAD,K] * W[N,K]^T (+bias) ----------------
// fp32 in/out; internally split-bf16 (hi+lo), 3-term MFMA for ~fp32 accuracy.
// Block tile 64x64, BK=32, 4 waves in 2x2, wave tile 32x32 (4 mfma tiles).
__global__ __launch_bounds__(256) void gemm_mfma_k(const float* __restrict__ A,
                                                   const float* __restrict__ W,
                                                   const float* __restrict__ bias,
                                                   float* __restrict__ C,
                                                   int N, int K) {
  __shared__ unsigned short Ah[2048], Al[2048], Wh[2048], Wl[2048];
  int row0 = blockIdx.x * 64, col0 = blockIdx.y * 64;
  int tid = threadIdx.x;
  int lane = tid & 63, wave = tid >> 6;
  int wm = (wave & 1) * 32, wn = (wave >> 1) * 32;
  int fr = lane & 15, fg = lane >> 4;          // fragment row-in-16, k-group
  int srow = tid >> 2, sq = tid & 3;           // staging: row 0..63, 8-col chunk
  const int sidx = srow * 32 + (((sq ^ ((srow >> 1) & 3))) << 3);  // XOR swizzle

  f32x4 acc[2][2] = {};

  for (int kk = 0; kk < K; kk += 32) {
    const float* pa = A + (size_t)(row0 + srow) * K + kk + sq * 8;
    const float* pw = W + (size_t)(col0 + srow) * K + kk + sq * 8;
    float av[8], wv[8];
    *(float4*)&av[0] = *(const float4*)&pa[0];
    *(float4*)&av[4] = *(const float4*)&pa[4];
    *(float4*)&wv[0] = *(const float4*)&pw[0];
    *(float4*)&wv[4] = *(const float4*)&pw[4];
    ush8 ahv, alv, whv, wlv;
#pragma unroll
    for (int j = 0; j < 8; ++j) {
      unsigned short h = bfh_(av[j]);
      ahv[j] = h;
      alv[j] = bfh_(av[j] - bf2f_(h));
      unsigned short g = bfh_(wv[j]);
      whv[j] = g;
      wlv[j] = bfh_(wv[j] - bf2f_(g));
    }
    __syncthreads();             // previous-iter reads done before overwrite
    *(ush8*)&Ah[sidx] = ahv;
    *(ush8*)&Al[sidx] = alv;
    *(ush8*)&Wh[sidx] = whv;
    *(ush8*)&Wl[sidx] = wlv;
    __syncthreads();

    short8_t ah[2], al[2], wh[2], wl[2];
#pragma unroll
    for (int i = 0; i < 2; ++i) {
      int ra = wm + i * 16 + fr;
      int oa = ra * 32 + ((fg ^ ((ra >> 1) & 3)) << 3);
      ah[i] = *(short8_t*)&Ah[oa];
      al[i] = *(short8_t*)&Al[oa];
      int rw = wn + i * 16 + fr;
      int ow = rw * 32 + ((fg ^ ((rw >> 1) & 3)) << 3);
      wh[i] = *(short8_t*)&Wh[ow];
      wl[i] = *(short8_t*)&Wl[ow];
    }
#pragma unroll
    for (int i = 0; i < 2; ++i)
#pragma unroll
      for (int j = 0; j < 2; ++j) {
        acc[i][j] = __builtin_amdgcn_mfma_f32_16x16x32_bf16(ah[i], wh[j], acc[i][j], 0, 0, 0);
        acc[i][j] = __builtin_amdgcn_mfma_f32_16x16x32_bf16(ah[i], wl[j], acc[i][j], 0, 0, 0);
        acc[i][j] = __builtin_amdgcn_mfma_f32_16x16x32_bf16(al[i], wh[j], acc[i][j], 0, 0, 0);
      }
  }

#pragma unroll
  for (int i = 0; i < 2; ++i)
#pragma unroll
    for (int j = 0; j < 2; ++j)
#pragma unroll
      for (int r = 0; r < 4; ++r) {
        int m = row0 + wm + i * 16 + (lane >> 4) * 4 + r;
        int n = col0 + wn + j * 16 + (lane & 15);
        float o = acc[i][j][r];
        if (bias) o += bias[n];
        C[(size_t)m * N + n] = o;
      }
}

// ---------------- fused residual-add + LayerNorm (1 wave per row of 192) ----------------
__global__ __launch_bounds__(64) void addln_k(float* __restrict__ res,
                                              const float* __restrict__ h,
                                              const float* __restrict__ w,
                                              const float* __restrict__ b,
                                              float* __restrict__ out) {
  int n = blockIdx.x;
  int t = threadIdx.x;
  float v[3];
  float s = 0.f;
#pragma unroll
  for (int i = 0; i < 3; ++i) {
    int d = t + 64 * i;
    float r = res[n * 192 + d] + h[(size_t)n * 192 + d];
    res[n * 192 + d] = r;
    v[i] = r;
    s += r;
  }
#pragma unroll
  for (int off = 32; off >= 1; off >>= 1) s += __shfl_xor(s, off);
  float mu = s * (1.f / 192.f);
  float q = 0.f;
#pragma unroll
  for (int i = 0; i < 3; ++i) { float dd = v[i] - mu; q += dd * dd; }
#pragma unroll
  for (int off = 32; off >= 1; off >>= 1) q += __shfl_xor(q, off);
  float inv = rsqrtf(q * (1.f / 192.f) + EPS);
#pragma unroll
  for (int i = 0; i < 3; ++i) {
    int d = t + 64 * i;
    out[(size_t)n * 192 + d] = (v[i] - mu) * inv * w[d] + b[d];
  }
}

// ---------------- fused conv4+SiLU + x_proj + dt_proj (one block per row) ----------------
__global__ __launch_bounds__(384) void convdbldt_k(const float* __restrict__ xz,
                                                   const float* __restrict__ cw,
                                                   const float* __restrict__ cb,
                                                   const float* __restrict__ xpw,
                                                   const float* __restrict__ dtw,
                                                   const float* __restrict__ dtb,
                                                   float* __restrict__ xc,
                                                   float* __restrict__ dbl,
                                                   float* __restrict__ dt) {
  __shared__ float xcl[384];
  __shared__ float dbll[44];
  int n = blockIdx.x;
  int b = n / LSEQ, l = n - b * LSEQ;
  int t = threadIdx.x;

  float acc = cb[t];
#pragma unroll
  for (int k = 0; k < 4; ++k) {
    int ll = l - 3 + k;
    if (ll >= 0) acc += xz[(size_t)(b * LSEQ + ll) * 768 + t] * cw[t * 4 + k];
  }
  float xcv = silu_(acc);
  xcl[t] = xcv;
  xc[(size_t)n * 384 + t] = xcv;
  __syncthreads();

  if (t < 352) {
    int e = t >> 3, part = t & 7;
    float s2 = 0.f;
    const float* wrow = xpw + e * 384 + part * 48;
    const float* xrow = xcl + part * 48;
#pragma unroll 8
    for (int k = 0; k < 48; ++k) s2 += xrow[k] * wrow[k];
    s2 += __shfl_xor(s2, 1);
    s2 += __shfl_xor(s2, 2);
    s2 += __shfl_xor(s2, 4);
    if (part == 0) {
      dbll[e] = s2;
      dbl[(size_t)n * 44 + e] = s2;
    }
  }
  __syncthreads();

  float a = dtb[t];
#pragma unroll
  for (int r = 0; r < 12; ++r) a += dbll[r] * dtw[t * 12 + r];
  float sp = fmaxf(a, 0.f) + log1pf(expf(-fabsf(a)));
  dt[(size_t)n * 384 + t] = sp;
}

// ---------------- chunked selective scan (runtime chunk count) ----------------
__global__ __launch_bounds__(256) void scanA_k(const float* __restrict__ dt,
                                               const float* __restrict__ xc,
                                               const float* __restrict__ dbl,
                                               const float* __restrict__ a_log,
                                               float* __restrict__ P,
                                               float* __restrict__ S,
                                               int tch) {
  int tid = blockIdx.x * 256 + threadIdx.x;
  int s = tid & 15;
  int g = tid >> 4;
  int c = g / 3072;
  int bd = g - c * 3072;
  int b = bd / 384, d = bd - b * 384;
  float A = -expf(a_log[d * 16 + s]);
  float h = 0.f, p = 1.f;
  int l0 = c * tch, base = b * LSEQ;
  for (int i = 0; i < tch; ++i) {
    int n = base + l0 + i;
    float dtv = dt[(size_t)n * 384 + d];
    float xcv = xc[(size_t)n * 384 + d];
    float Bv = dbl[(size_t)n * 44 + 12 + s];
    float a = expf(dtv * A);
    h = a * h + dtv * xcv * Bv;
    p *= a;
  }
  P[tid] = p;
  S[tid] = h;
}

__global__ __launch_bounds__(256) void scanC_k(const float* __restrict__ dt,
                                               const float* __restrict__ xc,
                                               const float* __restrict__ dbl,
                                               const float* __restrict__ xz,
                                               const float* __restrict__ a_log,
                                               const float* __restrict__ dpar,
                                               const float* __restrict__ P,
                                               const float* __restrict__ S,
                                               float* __restrict__ y,
                                               int tch) {
  int tid = blockIdx.x * 256 + threadIdx.x;
  int s = tid & 15;
  int g = tid >> 4;
  int c = g / 3072;
  int bd = g - c * 3072;
  int b = bd / 384, d = bd - b * 384;
  float A = -expf(a_log[d * 16 + s]);
  float Dp = dpar[d];
  float h = 0.f;
  for (int cc = 0; cc < c; ++cc) {
    int idx = ((cc * 3072 + bd) << 4) + s;
    h = P[idx] * h + S[idx];
  }
  int l0 = c * tch, base = b * LSEQ;
  for (int i = 0; i < tch; ++i) {
    int n = base + l0 + i;
    float dtv = dt[(size_t)n * 384 + d];
    float xcv = xc[(size_t)n * 384 + d];
    float Bv = dbl[(size_t)n * 44 + 12 + s];
    float Cv = dbl[(size_t)n * 44 + 28 + s];
    float a = expf(dtv * A);
    h = a * h + dtv * xcv * Bv;
    float ps = h * Cv;
    ps += __shfl_xor(ps, 1);
    ps += __shfl_xor(ps, 2);
    ps += __shfl_xor(ps, 4);
    ps += __shfl_xor(ps, 8);
    if (s == 0) {
      float zv = xz[(size_t)n * 768 + 384 + d];
      y[(size_t)n * 384 + d] = (ps + Dp * xcv) * silu_(zv);
    }
  }
}

// ---------------- fallback single-kernel scan ----------------
__global__ __launch_bounds__(256) void scan_k(const float* __restrict__ dt,
                                              const float* __restrict__ xc,
                                              const float* __restrict__ dbl,
                                              const float* __restrict__ xz,
                                              const float* __restrict__ a_log,
                                              const float* __restrict__ dpar,
                                              float* __restrict__ y) {
  int t = threadIdx.x;
  int s = t & 15;
  int g = (blockIdx.x * 256 + t) >> 4;
  int b = g / 384, d = g - b * 384;
  float A = -expf(a_log[d * 16 + s]);
  float Dp = dpar[d];
  float hst = 0.f;
  int base = b * LSEQ;
  for (int l = 0; l < LSEQ; ++l) {
    int n = base + l;
    float dtv = dt[(size_t)n * 384 + d];
    float xcv = xc[(size_t)n * 384 + d];
    float Bv = dbl[(size_t)n * 44 + 12 + s];
    float Cv = dbl[(size_t)n * 44 + 28 + s];
    float dA = expf(dtv * A);
    hst = dA * hst + dtv * xcv * Bv;
    float ps = hst * Cv;
    ps += __shfl_xor(ps, 1);
    ps += __shfl_xor(ps, 2);
    ps += __shfl_xor(ps, 4);
    ps += __shfl_xor(ps, 8);
    if (s == 0) {
      float zv = xz[(size_t)n * 768 + 384 + d];
      y[(size_t)n * 384 + d] = (ps + Dp * xcv) * silu_(zv);
    }
  }
}

extern "C" void kernel_launch(void* const* d_in, const int* in_sizes, int n_in,
                              void* d_out, int out_size, void* d_ws, size_t ws_size,
                              hipStream_t stream) {
  const float* x        = (const float*)d_in[0];
  const float* patch_w  = (const float*)d_in[1];
  const float* patch_b  = (const float*)d_in[2];
  const float* norm_w   = (const float*)d_in[3];
  const float* norm_b   = (const float*)d_in[4];
  const float* in_proj_w  = (const float*)d_in[5];
  const float* conv_w   = (const float*)d_in[6];
  const float* conv_b   = (const float*)d_in[7];
  const float* x_proj_w = (const float*)d_in[8];
  const float* dt_proj_w = (const float*)d_in[9];
  const float* dt_proj_b = (const float*)d_in[10];
  const float* A_log    = (const float*)d_in[11];
  const float* D_param  = (const float*)d_in[12];
  const float* out_proj_w = (const float*)d_in[13];
  const float* normf_w  = (const float*)d_in[14];
  const float* normf_b  = (const float*)d_in[15];
  float* out = (float*)d_out;
  float* ws = (float*)d_ws;

  // workspace layout (float offsets)
  float* res = ws;                     // 1568*192 = 301056
  float* h   = ws + 301056;            // 1600*192 = 307200
  float* hn  = ws + 608256;            // 1600*192 = 307200
  float* xz  = ws + 915456;            // 1600*768 = 1228800 (also im2col A)
  float* xc  = ws + 2144256;           // 1568*384 = 602112
  float* dbl = ws + 2746368;           // 1568*44  = 68992
  float* dt  = ws + 2815360;           // 1568*384 = 602112
  float* y   = ws + 3417472;           // 1600*384 = 614400
  float* Pb  = ws + 4031872;           // nch*3072*16
  // Sb follows Pb

  const size_t base_end = 4031872;
  int nch = 0;
  if (ws_size >= (base_end + 2ull * 14 * 49152) * 4) nch = 14;
  else if (ws_size >= (base_end + 2ull * 7 * 49152) * 4) nch = 7;
  float* Sb = Pb + (size_t)nch * 49152;
  int tch = nch ? LSEQ / nch : 0;

  // zero residual and pad rows (rows 1568..1599 of hn, xz, y stay zero all call)
  hipMemsetAsync(res, 0, 301056 * sizeof(float), stream);
  hipMemsetAsync(hn + (size_t)NROWS * 192, 0, (MPAD - NROWS) * 192 * sizeof(float), stream);
  hipMemsetAsync(xz + (size_t)NROWS * 768, 0, (MPAD - NROWS) * 768 * sizeof(float), stream);
  hipMemsetAsync(y  + (size_t)NROWS * 384, 0, (MPAD - NROWS) * 384 * sizeof(float), stream);

  // patch embedding: im2col + MFMA GEMM (M=1600, N=192, K=768) + bias
  im2col_k<<<dim3((NROWS * 768 + 255) / 256), 256, 0, stream>>>(x, xz);
  gemm_mfma_k<<<dim3(MPAD / 64, 192 / 64), 256, 0, stream>>>(xz, patch_w, patch_b, h, 192, 768);

  for (int L = 0; L < 24; ++L) {
    addln_k<<<NROWS, 64, 0, stream>>>(res, h, norm_w + L * 192, norm_b + L * 192, hn);
    gemm_mfma_k<<<dim3(MPAD / 64, 768 / 64), 256, 0, stream>>>(
        hn, in_proj_w + (size_t)L * 768 * 192, nullptr, xz, 768, 192);
    convdbldt_k<<<NROWS, 384, 0, stream>>>(xz,
        conv_w + (size_t)L * 384 * 4, conv_b + (size_t)L * 384,
        x_proj_w + (size_t)L * 44 * 384,
        dt_proj_w + (size_t)L * 384 * 12, dt_proj_b + (size_t)L * 384,
        xc, dbl, dt);
    const float* al = A_log + (size_t)L * 384 * 16;
    const float* dp = D_param + (size_t)L * 384;
    if (nch) {
      scanA_k<<<dim3(nch * 192), 256, 0, stream>>>(dt, xc, dbl, al, Pb, Sb, tch);
      scanC_k<<<dim3(nch * 192), 256, 0, stream>>>(dt, xc, dbl, xz, al, dp, Pb, Sb, y, tch);
    } else {
      scan_k<<<dim3((8 * 384 * 16) / 256), 256, 0, stream>>>(dt, xc, dbl, xz, al, dp, y);
    }
    gemm_mfma_k<<<dim3(MPAD / 64, 192 / 64), 256, 0, stream>>>(
        y, out_proj_w + (size_t)L * 192 * 384, nullptr, h, 192, 384);
  }

  addln_k<<<NROWS, 64, 0, stream>>>(res, h, normf_w, normf_b, out);
}

// Round 5
// 1701.724 us; speedup vs baseline: 3.2000x; 1.1701x over previous
//
#include <hip/hip_runtime.h>

#define NROWS 1568      // BATCH * L = 8 * 196
#define MPAD  1600      // padded rows for 64-row GEMM tiles
#define LSEQ  196
#define EPS   1e-5f
#define TCH   14        // chunk length
#define NCH   14        // chunks per sequence (TCH*NCH == LSEQ)

typedef __attribute__((ext_vector_type(8))) short short8_t;   // 8 bf16
typedef __attribute__((ext_vector_type(8))) unsigned short ush8;
typedef __attribute__((ext_vector_type(4))) float f32x4;

__device__ __forceinline__ float silu_(float x) { return x / (1.f + expf(-x)); }

__device__ __forceinline__ unsigned short bfh_(float f) {
  unsigned u = __float_as_uint(f);
  unsigned r = (u + 0x7FFFu + ((u >> 16) & 1u)) >> 16;
  return (unsigned short)r;
}
__device__ __forceinline__ float bf2f_(unsigned short h) {
  unsigned u = ((unsigned)h) << 16;
  return __uint_as_float(u);
}

// ---------------- im2col for patch embedding ----------------
__global__ __launch_bounds__(256) void im2col_k(const float* __restrict__ x,
                                                float* __restrict__ A) {
  int idx = blockIdx.x * 256 + threadIdx.x;
  if (idx >= NROWS * 768) return;
  int m = idx / 768, r = idx - m * 768;
  int b = m / LSEQ, l = m - b * LSEQ;
  int ph = l / 14, pw = l - ph * 14;
  int c = r >> 8, rem = r & 255, i = rem >> 4, j = rem & 15;
  A[idx] = x[((b * 3 + c) * 224 + ph * 16 + i) * 224 + pw * 16 + j];
}

// ---------------- MFMA GEMM: C[MPAD,N] = A[MPAD,K] * W[N,K]^T (+bias) ----------------
// fp32 in/out; split-bf16 (hi+lo), 3-term MFMA ~fp32 accuracy.
__global__ __launch_bounds__(256) void gemm_mfma_k(const float* __restrict__ A,
                                                   const float* __restrict__ W,
                                                   const float* __restrict__ bias,
                                                   float* __restrict__ C,
                                                   int N, int K) {
  __shared__ unsigned short Ah[2048], Al[2048], Wh[2048], Wl[2048];
  int row0 = blockIdx.x * 64, col0 = blockIdx.y * 64;
  int tid = threadIdx.x;
  int lane = tid & 63, wave = tid >> 6;
  int wm = (wave & 1) * 32, wn = (wave >> 1) * 32;
  int fr = lane & 15, fg = lane >> 4;
  int srow = tid >> 2, sq = tid & 3;
  const int sidx = srow * 32 + (((sq ^ ((srow >> 1) & 3))) << 3);

  f32x4 acc[2][2] = {};

  for (int kk = 0; kk < K; kk += 32) {
    const float* pa = A + (size_t)(row0 + srow) * K + kk + sq * 8;
    const float* pw = W + (size_t)(col0 + srow) * K + kk + sq * 8;
    float av[8], wv[8];
    *(float4*)&av[0] = *(const float4*)&pa[0];
    *(float4*)&av[4] = *(const float4*)&pa[4];
    *(float4*)&wv[0] = *(const float4*)&pw[0];
    *(float4*)&wv[4] = *(const float4*)&pw[4];
    ush8 ahv, alv, whv, wlv;
#pragma unroll
    for (int j = 0; j < 8; ++j) {
      unsigned short h = bfh_(av[j]);
      ahv[j] = h;
      alv[j] = bfh_(av[j] - bf2f_(h));
      unsigned short g = bfh_(wv[j]);
      whv[j] = g;
      wlv[j] = bfh_(wv[j] - bf2f_(g));
    }
    __syncthreads();
    *(ush8*)&Ah[sidx] = ahv;
    *(ush8*)&Al[sidx] = alv;
    *(ush8*)&Wh[sidx] = whv;
    *(ush8*)&Wl[sidx] = wlv;
    __syncthreads();

    short8_t ah[2], al[2], wh[2], wl[2];
#pragma unroll
    for (int i = 0; i < 2; ++i) {
      int ra = wm + i * 16 + fr;
      int oa = ra * 32 + ((fg ^ ((ra >> 1) & 3)) << 3);
      ah[i] = *(short8_t*)&Ah[oa];
      al[i] = *(short8_t*)&Al[oa];
      int rw = wn + i * 16 + fr;
      int ow = rw * 32 + ((fg ^ ((rw >> 1) & 3)) << 3);
      wh[i] = *(short8_t*)&Wh[ow];
      wl[i] = *(short8_t*)&Wl[ow];
    }
#pragma unroll
    for (int i = 0; i < 2; ++i)
#pragma unroll
      for (int j = 0; j < 2; ++j) {
        acc[i][j] = __builtin_amdgcn_mfma_f32_16x16x32_bf16(ah[i], wh[j], acc[i][j], 0, 0, 0);
        acc[i][j] = __builtin_amdgcn_mfma_f32_16x16x32_bf16(ah[i], wl[j], acc[i][j], 0, 0, 0);
        acc[i][j] = __builtin_amdgcn_mfma_f32_16x16x32_bf16(al[i], wh[j], acc[i][j], 0, 0, 0);
      }
  }

#pragma unroll
  for (int i = 0; i < 2; ++i)
#pragma unroll
    for (int j = 0; j < 2; ++j)
#pragma unroll
      for (int r = 0; r < 4; ++r) {
        int m = row0 + wm + i * 16 + (lane >> 4) * 4 + r;
        int n = col0 + wn + j * 16 + (lane & 15);
        float o = acc[i][j][r];
        if (bias) o += bias[n];
        C[(size_t)m * N + n] = o;
      }
}

// ---------------- fused residual-add + LayerNorm (1 wave per row of 192) ----------------
__global__ __launch_bounds__(64) void addln_k(float* __restrict__ res,
                                              const float* __restrict__ h,
                                              const float* __restrict__ w,
                                              const float* __restrict__ b,
                                              float* __restrict__ out) {
  int n = blockIdx.x;
  int t = threadIdx.x;
  float v[3];
  float s = 0.f;
#pragma unroll
  for (int i = 0; i < 3; ++i) {
    int d = t + 64 * i;
    float r = res[n * 192 + d] + h[(size_t)n * 192 + d];
    res[n * 192 + d] = r;
    v[i] = r;
    s += r;
  }
#pragma unroll
  for (int off = 32; off >= 1; off >>= 1) s += __shfl_xor(s, off);
  float mu = s * (1.f / 192.f);
  float q = 0.f;
#pragma unroll
  for (int i = 0; i < 3; ++i) { float dd = v[i] - mu; q += dd * dd; }
#pragma unroll
  for (int off = 32; off >= 1; off >>= 1) q += __shfl_xor(q, off);
  float inv = rsqrtf(q * (1.f / 192.f) + EPS);
#pragma unroll
  for (int i = 0; i < 3; ++i) {
    int d = t + 64 * i;
    out[(size_t)n * 192 + d] = (v[i] - mu) * inv * w[d] + b[d];
  }
}

// ---------------- fused conv4+SiLU + x_proj + dt_proj (one block per row) ----------------
__global__ __launch_bounds__(384) void convdbldt_k(const float* __restrict__ xz,
                                                   const float* __restrict__ cw,
                                                   const float* __restrict__ cb,
                                                   const float* __restrict__ xpw,
                                                   const float* __restrict__ dtw,
                                                   const float* __restrict__ dtb,
                                                   float* __restrict__ xc,
                                                   float* __restrict__ dbl,
                                                   float* __restrict__ dt) {
  __shared__ __align__(16) float xcl[384];
  __shared__ __align__(16) float dbll[48];
  int n = blockIdx.x;
  int b = n / LSEQ, l = n - b * LSEQ;
  int t = threadIdx.x;

  float acc = cb[t];
#pragma unroll
  for (int k = 0; k < 4; ++k) {
    int ll = l - 3 + k;
    if (ll >= 0) acc += xz[(size_t)(b * LSEQ + ll) * 768 + t] * cw[t * 4 + k];
  }
  float xcv = silu_(acc);
  xcl[t] = xcv;
  xc[(size_t)n * 384 + t] = xcv;
  __syncthreads();

  if (t < 352) {
    int e = t >> 3, part = t & 7;
    const float4* w4 = (const float4*)(xpw + e * 384 + part * 48);
    const float4* x4 = (const float4*)(xcl + part * 48);
    float s2 = 0.f;
#pragma unroll
    for (int k = 0; k < 12; ++k) {
      float4 a4 = x4[k], b4 = w4[k];
      s2 += a4.x * b4.x + a4.y * b4.y + a4.z * b4.z + a4.w * b4.w;
    }
    s2 += __shfl_xor(s2, 1);
    s2 += __shfl_xor(s2, 2);
    s2 += __shfl_xor(s2, 4);
    if (part == 0) {
      dbll[e] = s2;
      dbl[(size_t)n * 44 + e] = s2;
    }
  }
  __syncthreads();

  float a = dtb[t];
  {
    const float4* dw4 = (const float4*)(dtw + t * 12);
    const float4* bb4 = (const float4*)(&dbll[0]);
#pragma unroll
    for (int k = 0; k < 3; ++k) {
      float4 wv = dw4[k], bv = bb4[k];
      a += wv.x * bv.x + wv.y * bv.y + wv.z * bv.z + wv.w * bv.w;
    }
  }
  float sp = fmaxf(a, 0.f) + log1pf(expf(-fabsf(a)));
  dt[(size_t)n * 384 + t] = sp;
}

// ---------------- fused single-kernel chunked scan ----------------
// block = 448 threads: 2 (b,d) pairs x (14 chunks x 16 states)
// pass1: local chunk scan, cache a,u,C,D*xc,silu(z) in regs
// prefix: 4-step Hillis-Steele over affine maps in LDS
// pass2: replay from regs, shfl-reduce over s, emit gated y
__global__ __launch_bounds__(448) void scanF_k(const float* __restrict__ dt,
                                               const float* __restrict__ xc,
                                               const float* __restrict__ dbl,
                                               const float* __restrict__ xz,
                                               const float* __restrict__ a_log,
                                               const float* __restrict__ dpar,
                                               float* __restrict__ y) {
  __shared__ float Pl[2][NCH][17];
  __shared__ float Sl[2][NCH][17];
  int t = threadIdx.x;
  int p = t / 224;
  int r = t - p * 224;
  int c = r >> 4, s = r & 15;
  int bd = blockIdx.x * 2 + p;
  int b = bd / 384, d = bd - b * 384;
  float A = -expf(a_log[d * 16 + s]);
  float Dp = dpar[d];

  float a_c[TCH], u_c[TCH], C_c[TCH], dx_c[TCH], gz_c[TCH];
  float h = 0.f, pr = 1.f;
  int base = b * LSEQ + c * TCH;
#pragma unroll
  for (int i = 0; i < TCH; ++i) {
    int n = base + i;
    float dtv = dt[(size_t)n * 384 + d];
    float xcv = xc[(size_t)n * 384 + d];
    float Bv  = dbl[(size_t)n * 44 + 12 + s];
    float Cv  = dbl[(size_t)n * 44 + 28 + s];
    float zv  = xz[(size_t)n * 768 + 384 + d];
    float a = expf(dtv * A);
    float u = dtv * xcv * Bv;
    h = a * h + u;
    pr *= a;
    a_c[i] = a; u_c[i] = u; C_c[i] = Cv;
    dx_c[i] = Dp * xcv; gz_c[i] = silu_(zv);
  }
  Pl[p][c][s] = pr;
  Sl[p][c][s] = h;
  __syncthreads();

#pragma unroll
  for (int off = 1; off < NCH; off <<= 1) {
    float Pp = 1.f, Sp = 0.f;
    if (c >= off) { Pp = Pl[p][c - off][s]; Sp = Sl[p][c - off][s]; }
    __syncthreads();
    if (c >= off) {
      float Pc = Pl[p][c][s], Sc = Sl[p][c][s];
      Pl[p][c][s] = Pc * Pp;
      Sl[p][c][s] = Pc * Sp + Sc;
    }
    __syncthreads();
  }

  h = (c > 0) ? Sl[p][c - 1][s] : 0.f;
#pragma unroll
  for (int i = 0; i < TCH; ++i) {
    h = a_c[i] * h + u_c[i];
    float ps = h * C_c[i];
    ps += __shfl_xor(ps, 1);
    ps += __shfl_xor(ps, 2);
    ps += __shfl_xor(ps, 4);
    ps += __shfl_xor(ps, 8);
    if (s == 0) {
      int n = base + i;
      y[(size_t)n * 384 + d] = (ps + dx_c[i]) * gz_c[i];
    }
  }
}

extern "C" void kernel_launch(void* const* d_in, const int* in_sizes, int n_in,
                              void* d_out, int out_size, void* d_ws, size_t ws_size,
                              hipStream_t stream) {
  const float* x        = (const float*)d_in[0];
  const float* patch_w  = (const float*)d_in[1];
  const float* patch_b  = (const float*)d_in[2];
  const float* norm_w   = (const float*)d_in[3];
  const float* norm_b   = (const float*)d_in[4];
  const float* in_proj_w  = (const float*)d_in[5];
  const float* conv_w   = (const float*)d_in[6];
  const float* conv_b   = (const float*)d_in[7];
  const float* x_proj_w = (const float*)d_in[8];
  const float* dt_proj_w = (const float*)d_in[9];
  const float* dt_proj_b = (const float*)d_in[10];
  const float* A_log    = (const float*)d_in[11];
  const float* D_param  = (const float*)d_in[12];
  const float* out_proj_w = (const float*)d_in[13];
  const float* normf_w  = (const float*)d_in[14];
  const float* normf_b  = (const float*)d_in[15];
  float* out = (float*)d_out;
  float* ws = (float*)d_ws;

  // workspace layout (float offsets)
  float* res = ws;                     // 1568*192 = 301056
  float* h   = ws + 301056;            // 1600*192 = 307200
  float* hn  = ws + 608256;            // 1600*192 = 307200
  float* xz  = ws + 915456;            // 1600*768 = 1228800 (also im2col A)
  float* xc  = ws + 2144256;           // 1568*384 = 602112
  float* dbl = ws + 2746368;           // 1568*44  = 68992
  float* dt  = ws + 2815360;           // 1568*384 = 602112
  float* y   = ws + 3417472;           // 1600*384 = 614400

  // zero residual and pad rows (gemm reads pads; hn/y pads stay zero within a call)
  hipMemsetAsync(res, 0, 301056 * sizeof(float), stream);
  hipMemsetAsync(hn + (size_t)NROWS * 192, 0, (MPAD - NROWS) * 192 * sizeof(float), stream);
  hipMemsetAsync(xz + (size_t)NROWS * 768, 0, (MPAD - NROWS) * 768 * sizeof(float), stream);
  hipMemsetAsync(y  + (size_t)NROWS * 384, 0, (MPAD - NROWS) * 384 * sizeof(float), stream);

  // patch embedding: im2col + MFMA GEMM (M=1600, N=192, K=768) + bias
  im2col_k<<<dim3((NROWS * 768 + 255) / 256), 256, 0, stream>>>(x, xz);
  gemm_mfma_k<<<dim3(MPAD / 64, 192 / 64), 256, 0, stream>>>(xz, patch_w, patch_b, h, 192, 768);

  for (int L = 0; L < 24; ++L) {
    addln_k<<<NROWS, 64, 0, stream>>>(res, h, norm_w + L * 192, norm_b + L * 192, hn);
    gemm_mfma_k<<<dim3(MPAD / 64, 768 / 64), 256, 0, stream>>>(
        hn, in_proj_w + (size_t)L * 768 * 192, nullptr, xz, 768, 192);
    convdbldt_k<<<NROWS, 384, 0, stream>>>(xz,
        conv_w + (size_t)L * 384 * 4, conv_b + (size_t)L * 384,
        x_proj_w + (size_t)L * 44 * 384,
        dt_proj_w + (size_t)L * 384 * 12, dt_proj_b + (size_t)L * 384,
        xc, dbl, dt);
    scanF_k<<<dim3(8 * 384 / 2), 448, 0, stream>>>(dt, xc, dbl, xz,
        A_log + (size_t)L * 384 * 16, D_param + (size_t)L * 384, y);
    gemm_mfma_k<<<dim3(MPAD / 64, 192 / 64), 256, 0, stream>>>(
        y, out_proj_w + (size_t)L * 192 * 384, nullptr, h, 192, 384);
  }

  addln_k<<<NROWS, 64, 0, stream>>>(res, h, normf_w, normf_b, out);
}

// Round 6
// 1668.948 us; speedup vs baseline: 3.2628x; 1.0196x over previous
//
#include <hip/hip_runtime.h>

#define NROWS 1568      // BATCH * L = 8 * 196
#define MPAD  1600      // padded rows for 64-row GEMM tiles
#define LSEQ  196
#define EPS   1e-5f
#define TCH   14        // chunk length
#define NCH   14        // chunks per sequence (TCH*NCH == LSEQ)

typedef __attribute__((ext_vector_type(8))) short short8_t;   // 8 bf16
typedef __attribute__((ext_vector_type(8))) unsigned short ush8;
typedef __attribute__((ext_vector_type(4))) float f32x4;
typedef unsigned short ush;

__device__ __forceinline__ float silu_(float x) { return x / (1.f + expf(-x)); }

__device__ __forceinline__ ush bfh_(float f) {
  unsigned u = __float_as_uint(f);
  unsigned r = (u + 0x7FFFu + ((u >> 16) & 1u)) >> 16;
  return (ush)r;
}
__device__ __forceinline__ float bf2f_(ush h) {
  unsigned u = ((unsigned)h) << 16;
  return __uint_as_float(u);
}

// ---------------- split fp32 -> bf16 hi/lo (weights, once per call) ----------------
__global__ __launch_bounds__(256) void wsplit_k(const float* __restrict__ src,
                                                ush* __restrict__ hi,
                                                ush* __restrict__ lo,
                                                int n8) {
  int i = blockIdx.x * 256 + threadIdx.x;
  if (i >= n8) return;
  float v[8];
  *(float4*)&v[0] = *(const float4*)(src + (size_t)i * 8);
  *(float4*)&v[4] = *(const float4*)(src + (size_t)i * 8 + 4);
  ush8 h8, l8;
#pragma unroll
  for (int j = 0; j < 8; ++j) {
    ush h = bfh_(v[j]);
    h8[j] = h;
    l8[j] = bfh_(v[j] - bf2f_(h));
  }
  *(ush8*)&hi[(size_t)i * 8] = h8;
  *(ush8*)&lo[(size_t)i * 8] = l8;
}

// ---------------- zero res + pad rows of bf16 activation buffers ----------------
__global__ __launch_bounds__(256) void zeros_k(float* __restrict__ res,
                                               ush* __restrict__ a_h, ush* __restrict__ a_l,
                                               ush* __restrict__ hn_h, ush* __restrict__ hn_l,
                                               ush* __restrict__ y_h, ush* __restrict__ y_l) {
  int i = blockIdx.x * 256 + threadIdx.x;
  ush8 z = {};
  if (i < 75264) ((float4*)res)[i] = float4{0.f, 0.f, 0.f, 0.f};
  if (i < 3072) {
    ((ush8*)(a_h + (size_t)NROWS * 768))[i] = z;
    ((ush8*)(a_l + (size_t)NROWS * 768))[i] = z;
  }
  if (i < 768) {
    ((ush8*)(hn_h + (size_t)NROWS * 192))[i] = z;
    ((ush8*)(hn_l + (size_t)NROWS * 192))[i] = z;
  }
  if (i < 1536) {
    ((ush8*)(y_h + (size_t)NROWS * 384))[i] = z;
    ((ush8*)(y_l + (size_t)NROWS * 384))[i] = z;
  }
}

// ---------------- im2col for patch embedding, bf16 hi/lo out ----------------
// 8 consecutive r share (c,i) and j-octet -> contiguous x reads.
__global__ __launch_bounds__(256) void im2col_k(const float* __restrict__ x,
                                                ush* __restrict__ Ah,
                                                ush* __restrict__ Al) {
  int i8 = blockIdx.x * 256 + threadIdx.x;
  if (i8 >= NROWS * 768 / 8) return;
  int idx = i8 * 8;
  int m = idx / 768, r = idx - m * 768;
  int b = m / LSEQ, l = m - b * LSEQ;
  int ph = l / 14, pw = l - ph * 14;
  int c = r >> 8, rem = r & 255, ii = rem >> 4, j = rem & 15;
  const float* src = &x[((b * 3 + c) * 224 + ph * 16 + ii) * 224 + pw * 16 + j];
  float v[8];
  *(float4*)&v[0] = *(const float4*)&src[0];
  *(float4*)&v[4] = *(const float4*)&src[4];
  ush8 h8, l8;
#pragma unroll
  for (int k = 0; k < 8; ++k) {
    ush h = bfh_(v[k]);
    h8[k] = h;
    l8[k] = bfh_(v[k] - bf2f_(h));
  }
  *(ush8*)&Ah[idx] = h8;
  *(ush8*)&Al[idx] = l8;
}

// ---------------- MFMA GEMM on pre-split bf16: C[MPAD,N] = A[MPAD,K]*W[N,K]^T (+bias) ----
// 64x64 tile, BK=32, 4 waves 2x2, 3-term split-bf16 (ah*wh + ah*wl + al*wh).
__global__ __launch_bounds__(256) void gemm_bf_k(const ush* __restrict__ Ah_g,
                                                 const ush* __restrict__ Al_g,
                                                 const ush* __restrict__ Wh_g,
                                                 const ush* __restrict__ Wl_g,
                                                 const float* __restrict__ bias,
                                                 float* __restrict__ C,
                                                 int N, int K) {
  __shared__ ush Ah[2048], Al[2048], Wh[2048], Wl[2048];
  int row0 = blockIdx.x * 64, col0 = blockIdx.y * 64;
  int tid = threadIdx.x;
  int lane = tid & 63, wave = tid >> 6;
  int wm = (wave & 1) * 32, wn = (wave >> 1) * 32;
  int fr = lane & 15, fg = lane >> 4;
  int srow = tid >> 2, sch = tid & 3;
  const int sdst = srow * 32 + ((sch ^ ((srow >> 1) & 3)) << 3);  // swizzled LDS slot

  f32x4 acc[2][2] = {};

  for (int kk = 0; kk < K; kk += 32) {
    size_t ga = (size_t)(row0 + srow) * K + kk + sch * 8;
    size_t gw = (size_t)(col0 + srow) * K + kk + sch * 8;
    ush8 vah = *(const ush8*)&Ah_g[ga];
    ush8 val = *(const ush8*)&Al_g[ga];
    ush8 vwh = *(const ush8*)&Wh_g[gw];
    ush8 vwl = *(const ush8*)&Wl_g[gw];
    __syncthreads();
    *(ush8*)&Ah[sdst] = vah;
    *(ush8*)&Al[sdst] = val;
    *(ush8*)&Wh[sdst] = vwh;
    *(ush8*)&Wl[sdst] = vwl;
    __syncthreads();

    short8_t ah[2], al[2], wh[2], wl[2];
#pragma unroll
    for (int i = 0; i < 2; ++i) {
      int ra = wm + i * 16 + fr;
      int oa = ra * 32 + ((fg ^ ((ra >> 1) & 3)) << 3);
      ah[i] = *(short8_t*)&Ah[oa];
      al[i] = *(short8_t*)&Al[oa];
      int rw = wn + i * 16 + fr;
      int ow = rw * 32 + ((fg ^ ((rw >> 1) & 3)) << 3);
      wh[i] = *(short8_t*)&Wh[ow];
      wl[i] = *(short8_t*)&Wl[ow];
    }
#pragma unroll
    for (int i = 0; i < 2; ++i)
#pragma unroll
      for (int j = 0; j < 2; ++j) {
        acc[i][j] = __builtin_amdgcn_mfma_f32_16x16x32_bf16(ah[i], wh[j], acc[i][j], 0, 0, 0);
        acc[i][j] = __builtin_amdgcn_mfma_f32_16x16x32_bf16(ah[i], wl[j], acc[i][j], 0, 0, 0);
        acc[i][j] = __builtin_amdgcn_mfma_f32_16x16x32_bf16(al[i], wh[j], acc[i][j], 0, 0, 0);
      }
  }

#pragma unroll
  for (int i = 0; i < 2; ++i)
#pragma unroll
    for (int j = 0; j < 2; ++j)
#pragma unroll
      for (int r = 0; r < 4; ++r) {
        int m = row0 + wm + i * 16 + (lane >> 4) * 4 + r;
        int n = col0 + wn + j * 16 + (lane & 15);
        float o = acc[i][j][r];
        if (bias) o += bias[n];
        C[(size_t)m * N + n] = o;
      }
}

// ---------------- fused residual-add + LayerNorm -> split-bf16 out (per-layer) --------
__global__ __launch_bounds__(64) void addlnbf_k(float* __restrict__ res,
                                                const float* __restrict__ h,
                                                const float* __restrict__ w,
                                                const float* __restrict__ b,
                                                ush* __restrict__ out_h,
                                                ush* __restrict__ out_l) {
  int n = blockIdx.x;
  int t = threadIdx.x;
  float v[3];
  float s = 0.f;
#pragma unroll
  for (int i = 0; i < 3; ++i) {
    int d = t + 64 * i;
    float r = res[n * 192 + d] + h[(size_t)n * 192 + d];
    res[n * 192 + d] = r;
    v[i] = r;
    s += r;
  }
#pragma unroll
  for (int off = 32; off >= 1; off >>= 1) s += __shfl_xor(s, off);
  float mu = s * (1.f / 192.f);
  float q = 0.f;
#pragma unroll
  for (int i = 0; i < 3; ++i) { float dd = v[i] - mu; q += dd * dd; }
#pragma unroll
  for (int off = 32; off >= 1; off >>= 1) q += __shfl_xor(q, off);
  float inv = rsqrtf(q * (1.f / 192.f) + EPS);
#pragma unroll
  for (int i = 0; i < 3; ++i) {
    int d = t + 64 * i;
    float o = (v[i] - mu) * inv * w[d] + b[d];
    ush hh = bfh_(o);
    out_h[(size_t)n * 192 + d] = hh;
    out_l[(size_t)n * 192 + d] = bfh_(o - bf2f_(hh));
  }
}

// ---------------- final residual-add + LayerNorm -> fp32 out ----------------
__global__ __launch_bounds__(64) void addln_k(float* __restrict__ res,
                                              const float* __restrict__ h,
                                              const float* __restrict__ w,
                                              const float* __restrict__ b,
                                              float* __restrict__ out) {
  int n = blockIdx.x;
  int t = threadIdx.x;
  float v[3];
  float s = 0.f;
#pragma unroll
  for (int i = 0; i < 3; ++i) {
    int d = t + 64 * i;
    float r = res[n * 192 + d] + h[(size_t)n * 192 + d];
    res[n * 192 + d] = r;
    v[i] = r;
    s += r;
  }
#pragma unroll
  for (int off = 32; off >= 1; off >>= 1) s += __shfl_xor(s, off);
  float mu = s * (1.f / 192.f);
  float q = 0.f;
#pragma unroll
  for (int i = 0; i < 3; ++i) { float dd = v[i] - mu; q += dd * dd; }
#pragma unroll
  for (int off = 32; off >= 1; off >>= 1) q += __shfl_xor(q, off);
  float inv = rsqrtf(q * (1.f / 192.f) + EPS);
#pragma unroll
  for (int i = 0; i < 3; ++i) {
    int d = t + 64 * i;
    out[(size_t)n * 192 + d] = (v[i] - mu) * inv * w[d] + b[d];
  }
}

// ---------------- fused conv4+SiLU + x_proj + dt_proj (one block per row) ----------------
__global__ __launch_bounds__(384) void convdbldt_k(const float* __restrict__ xz,
                                                   const float* __restrict__ cw,
                                                   const float* __restrict__ cb,
                                                   const float* __restrict__ xpw,
                                                   const float* __restrict__ dtw,
                                                   const float* __restrict__ dtb,
                                                   float* __restrict__ xc,
                                                   float* __restrict__ dbl,
                                                   float* __restrict__ dt) {
  __shared__ __align__(16) float xcl[384];
  __shared__ __align__(16) float dbll[48];
  int n = blockIdx.x;
  int b = n / LSEQ, l = n - b * LSEQ;
  int t = threadIdx.x;

  float acc = cb[t];
#pragma unroll
  for (int k = 0; k < 4; ++k) {
    int ll = l - 3 + k;
    if (ll >= 0) acc += xz[(size_t)(b * LSEQ + ll) * 768 + t] * cw[t * 4 + k];
  }
  float xcv = silu_(acc);
  xcl[t] = xcv;
  xc[(size_t)n * 384 + t] = xcv;
  __syncthreads();

  if (t < 352) {
    int e = t >> 3, part = t & 7;
    const float4* w4 = (const float4*)(xpw + e * 384 + part * 48);
    const float4* x4 = (const float4*)(xcl + part * 48);
    float s2 = 0.f;
#pragma unroll
    for (int k = 0; k < 12; ++k) {
      float4 a4 = x4[k], b4 = w4[k];
      s2 += a4.x * b4.x + a4.y * b4.y + a4.z * b4.z + a4.w * b4.w;
    }
    s2 += __shfl_xor(s2, 1);
    s2 += __shfl_xor(s2, 2);
    s2 += __shfl_xor(s2, 4);
    if (part == 0) {
      dbll[e] = s2;
      dbl[(size_t)n * 44 + e] = s2;
    }
  }
  __syncthreads();

  float a = dtb[t];
  {
    const float4* dw4 = (const float4*)(dtw + t * 12);
    const float4* bb4 = (const float4*)(&dbll[0]);
#pragma unroll
    for (int k = 0; k < 3; ++k) {
      float4 wv = dw4[k], bv = bb4[k];
      a += wv.x * bv.x + wv.y * bv.y + wv.z * bv.z + wv.w * bv.w;
    }
  }
  float sp = fmaxf(a, 0.f) + log1pf(expf(-fabsf(a)));
  dt[(size_t)n * 384 + t] = sp;
}

// ---------------- fused single-kernel chunked scan, split-bf16 y out ----------------
__global__ __launch_bounds__(448) void scanF_k(const float* __restrict__ dt,
                                               const float* __restrict__ xc,
                                               const float* __restrict__ dbl,
                                               const float* __restrict__ xz,
                                               const float* __restrict__ a_log,
                                               const float* __restrict__ dpar,
                                               ush* __restrict__ y_h,
                                               ush* __restrict__ y_l) {
  __shared__ float Pl[2][NCH][17];
  __shared__ float Sl[2][NCH][17];
  int t = threadIdx.x;
  int p = t / 224;
  int r = t - p * 224;
  int c = r >> 4, s = r & 15;
  int bd = blockIdx.x * 2 + p;
  int b = bd / 384, d = bd - b * 384;
  float A = -expf(a_log[d * 16 + s]);
  float Dp = dpar[d];

  float a_c[TCH], u_c[TCH], C_c[TCH], dx_c[TCH], gz_c[TCH];
  float h = 0.f, pr = 1.f;
  int base = b * LSEQ + c * TCH;
#pragma unroll
  for (int i = 0; i < TCH; ++i) {
    int n = base + i;
    float dtv = dt[(size_t)n * 384 + d];
    float xcv = xc[(size_t)n * 384 + d];
    float Bv  = dbl[(size_t)n * 44 + 12 + s];
    float Cv  = dbl[(size_t)n * 44 + 28 + s];
    float zv  = xz[(size_t)n * 768 + 384 + d];
    float a = expf(dtv * A);
    float u = dtv * xcv * Bv;
    h = a * h + u;
    pr *= a;
    a_c[i] = a; u_c[i] = u; C_c[i] = Cv;
    dx_c[i] = Dp * xcv; gz_c[i] = silu_(zv);
  }
  Pl[p][c][s] = pr;
  Sl[p][c][s] = h;
  __syncthreads();

#pragma unroll
  for (int off = 1; off < NCH; off <<= 1) {
    float Pp = 1.f, Sp = 0.f;
    if (c >= off) { Pp = Pl[p][c - off][s]; Sp = Sl[p][c - off][s]; }
    __syncthreads();
    if (c >= off) {
      float Pc = Pl[p][c][s], Sc = Sl[p][c][s];
      Pl[p][c][s] = Pc * Pp;
      Sl[p][c][s] = Pc * Sp + Sc;
    }
    __syncthreads();
  }

  h = (c > 0) ? Sl[p][c - 1][s] : 0.f;
#pragma unroll
  for (int i = 0; i < TCH; ++i) {
    h = a_c[i] * h + u_c[i];
    float ps = h * C_c[i];
    ps += __shfl_xor(ps, 1);
    ps += __shfl_xor(ps, 2);
    ps += __shfl_xor(ps, 4);
    ps += __shfl_xor(ps, 8);
    if (s == 0) {
      int n = base + i;
      float o = (ps + dx_c[i]) * gz_c[i];
      ush hh = bfh_(o);
      y_h[(size_t)n * 384 + d] = hh;
      y_l[(size_t)n * 384 + d] = bfh_(o - bf2f_(hh));
    }
  }
}

extern "C" void kernel_launch(void* const* d_in, const int* in_sizes, int n_in,
                              void* d_out, int out_size, void* d_ws, size_t ws_size,
                              hipStream_t stream) {
  const float* x        = (const float*)d_in[0];
  const float* patch_w  = (const float*)d_in[1];
  const float* patch_b  = (const float*)d_in[2];
  const float* norm_w   = (const float*)d_in[3];
  const float* norm_b   = (const float*)d_in[4];
  const float* in_proj_w  = (const float*)d_in[5];
  const float* conv_w   = (const float*)d_in[6];
  const float* conv_b   = (const float*)d_in[7];
  const float* x_proj_w = (const float*)d_in[8];
  const float* dt_proj_w = (const float*)d_in[9];
  const float* dt_proj_b = (const float*)d_in[10];
  const float* A_log    = (const float*)d_in[11];
  const float* D_param  = (const float*)d_in[12];
  const float* out_proj_w = (const float*)d_in[13];
  const float* normf_w  = (const float*)d_in[14];
  const float* normf_b  = (const float*)d_in[15];
  float* out = (float*)d_out;
  float* ws = (float*)d_ws;

  // fp32 workspace (float offsets)
  float* res = ws;                     // 301056
  float* xz  = ws + 301056;            // 1600*768 = 1228800
  float* xc  = ws + 1529856;           // 1568*384 = 602112
  float* dbl = ws + 2131968;           // 1568*44  = 68992
  float* dt  = ws + 2200960;           // 1568*384 = 602112
  float* h   = ws + 2803072;           // 1600*192 = 307200
  // bf16 area (ush offsets from here)
  ush* ub = (ush*)(ws + 3110272);
  ush* a_h  = ub;                      // 1600*768
  ush* a_l  = ub + 1228800;
  ush* hn_h = ub + 2457600;            // 1600*192
  ush* hn_l = ub + 2764800;
  ush* y_h  = ub + 3072000;            // 1600*384
  ush* y_l  = ub + 3686400;
  ush* pw_h = ub + 4300800;            // 192*768
  ush* pw_l = ub + 4448256;
  ush* ipw_h = ub + 4595712;           // 24*768*192
  ush* ipw_l = ub + 8134656;
  ush* opw_h = ub + 11673600;          // 24*192*384
  ush* opw_l = ub + 13443072;          // end 15212544 ush

  // one-shot per call: zero res + bf16 pad rows; split weights to bf16 hi/lo
  zeros_k<<<294, 256, 0, stream>>>(res, a_h, a_l, hn_h, hn_l, y_h, y_l);
  wsplit_k<<<(147456 / 8 + 255) / 256, 256, 0, stream>>>(patch_w, pw_h, pw_l, 147456 / 8);
  wsplit_k<<<(3538944 / 8 + 255) / 256, 256, 0, stream>>>(in_proj_w, ipw_h, ipw_l, 3538944 / 8);
  wsplit_k<<<(1769472 / 8 + 255) / 256, 256, 0, stream>>>(out_proj_w, opw_h, opw_l, 1769472 / 8);

  // patch embedding: im2col(bf16) + GEMM (M=1600, N=192, K=768) + bias
  im2col_k<<<(NROWS * 768 / 8 + 255) / 256, 256, 0, stream>>>(x, a_h, a_l);
  gemm_bf_k<<<dim3(MPAD / 64, 192 / 64), 256, 0, stream>>>(a_h, a_l, pw_h, pw_l, patch_b, h, 192, 768);

  for (int L = 0; L < 24; ++L) {
    addlnbf_k<<<NROWS, 64, 0, stream>>>(res, h, norm_w + L * 192, norm_b + L * 192, hn_h, hn_l);
    gemm_bf_k<<<dim3(MPAD / 64, 768 / 64), 256, 0, stream>>>(
        hn_h, hn_l, ipw_h + (size_t)L * 147456, ipw_l + (size_t)L * 147456, nullptr, xz, 768, 192);
    convdbldt_k<<<NROWS, 384, 0, stream>>>(xz,
        conv_w + (size_t)L * 384 * 4, conv_b + (size_t)L * 384,
        x_proj_w + (size_t)L * 44 * 384,
        dt_proj_w + (size_t)L * 384 * 12, dt_proj_b + (size_t)L * 384,
        xc, dbl, dt);
    scanF_k<<<dim3(8 * 384 / 2), 448, 0, stream>>>(dt, xc, dbl, xz,
        A_log + (size_t)L * 384 * 16, D_param + (size_t)L * 384, y_h, y_l);
    gemm_bf_k<<<dim3(MPAD / 64, 192 / 64), 256, 0, stream>>>(
        y_h, y_l, opw_h + (size_t)L * 73728, opw_l + (size_t)L * 73728, nullptr, h, 192, 384);
  }

  addln_k<<<NROWS, 64, 0, stream>>>(res, h, normf_w, normf_b, out);
}